// Round 16
// baseline (1276.737 us; speedup 1.0000x reference)
//
#include <hip/hip_runtime.h>
#include <math.h>
#include <type_traits>

// Fused MLP head with BINARY output (per-row top-k gate + 0.2 hardlim).
// Verified architecture: bf16-split(3-product) MFMA fast pass -> logit-margin
// flags (TAU=1e-4) -> streaming fp64 repair of flagged rows -> exact gate.
// r15: both GEMMs unified on the r12-verified 256x256/2x64KB-buf kernel
//      (template OUT_SPLIT, runtime N/K/nbn). GEMM2: A-panel re-reads halve
//      (nbn 4->2), MFMA/barrier x2 vs the old 256x128 path. GEMM1 unchanged
//      (58.6% MfmaUtil = 94% of the m201-class structural ceiling).

#define BM 128
#define BN 128
#define BK 16      // fp64 fallback K-step

#define TAU   1.0e-4f
#define L02F -1.3862943611198906f   /* ln(0.2/0.8) */

typedef __attribute__((ext_vector_type(8))) short  bf16x8;
typedef __attribute__((ext_vector_type(8))) ushort u16x8;
typedef __attribute__((ext_vector_type(4))) float  f32x4;

__device__ inline ushort bfhi(float f)   { return (ushort)(__float_as_uint(f) >> 16); }
__device__ inline float  bfhif(float f)  { return __uint_as_float(__float_as_uint(f) & 0xFFFF0000u); }

__device__ inline void gload_lds16(const void* g, void* l) {
    __builtin_amdgcn_global_load_lds(
        (const __attribute__((address_space(1))) unsigned int*)g,
        (__attribute__((address_space(3))) unsigned int*)l, 16, 0, 0);
}

// ---------------- fused fp32 -> (hi,lo) bf16 split over 3 arrays -----------
__global__ __launch_bounds__(256) void split3_kernel(
    const float* __restrict__ s0, ushort* __restrict__ h0, ushort* __restrict__ l0, size_t n0,
    const float* __restrict__ s1, ushort* __restrict__ h1, ushort* __restrict__ l1, size_t n1,
    const float* __restrict__ s2, ushort* __restrict__ h2, ushort* __restrict__ l2, size_t n2,
    int* cnt)
{
    if (blockIdx.x == 0 && threadIdx.x == 0) *cnt = 0;
    size_t i = (size_t)blockIdx.x * 256 + threadIdx.x;
    const size_t stride = (size_t)gridDim.x * 256;
    const size_t total = n0 + n1 + n2;
    for (; i < total; i += stride) {
        const float* s; ushort* h; ushort* l; size_t j;
        if (i < n0)            { s = s0; h = h0; l = l0; j = i; }
        else if (i < n0 + n1)  { s = s1; h = h1; l = l1; j = i - n0; }
        else                   { s = s2; h = h2; l = l2; j = i - n0 - n1; }
        float4 v = ((const float4*)s)[j];
        ushort4 hh, ll;
        hh.x = bfhi(v.x); ll.x = bfhi(v.x - bfhif(v.x));
        hh.y = bfhi(v.y); ll.y = bfhi(v.y - bfhif(v.y));
        hh.z = bfhi(v.z); ll.z = bfhi(v.z - bfhif(v.z));
        hh.w = bfhi(v.w); ll.w = bfhi(v.w - bfhif(v.w));
        ((ushort4*)h)[j] = hh;
        ((ushort4*)l)[j] = ll;
    }
}

// ---------------- unified 256x256 split-GEMM (r12-verified structure) ------
// C = epilogue(A @ W^T + bias); A (Mx K) and W (N x K) pre-split bf16 hi/lo.
// Tile 256x256, BK=32, 512 thr (8 waves, 4m x 2n), 2 x 64KB LDS bufs.
// OUT_SPLIT 1: relu -> (Chi, Clo) pair, ld=N. 0: fp32 -> C32, ld=N.
// grid = 8 * nbmx * nbn blocks; per-XCD row-tiles nbmx = (grid>>3)/nbn.
template<int OUT_SPLIT>
__global__ __launch_bounds__(512, 2) void bgemm_256(
    const ushort* __restrict__ aH, const ushort* __restrict__ aL,
    const ushort* __restrict__ wH, const ushort* __restrict__ wL,
    const float* __restrict__ bias,
    ushort* __restrict__ Chi, ushort* __restrict__ Clo,
    float* __restrict__ C32,
    int N, int K, int nbn)
{
    __shared__ ushort lds[65536];          // 2 bufs x 32768 ush (64 KB each)
    const int t    = threadIdx.x;
    const int lane = t & 63;
    const int wave = t >> 6;
    const int wr   = wave >> 1;            // 0..3 (64-row block)
    const int wc   = wave & 1;             // 0..1 (128-col block)
    const int l15  = lane & 15;
    const int l4   = lane >> 4;

    // XCD: contiguous bm per XCD, bn fastest.
    const int bid  = blockIdx.x;
    const int xcd  = bid & 7;
    const int j    = bid >> 3;
    const int nbmx = (gridDim.x >> 3) / nbn;
    const int bm   = xcd * nbmx + j / nbn;
    const int bn   = j % nbn;

    // staging: per wave 8 gloads, rows wave*32..+31 of each region
    const int cq = lane & 3;
    const int r0 = wave * 32 + (lane >> 2);
    const int r1 = r0 + 16;
    const size_t sw0 = (size_t)((cq ^ ((r0 >> 1) & 3)) * 8);
    const size_t sw1 = (size_t)((cq ^ ((r1 >> 1) & 3)) * 8);
    const size_t gA0 = (size_t)(bm * 256 + r0) * K + sw0;
    const size_t gA1 = (size_t)(bm * 256 + r1) * K + sw1;
    const size_t gB0 = (size_t)(bn * 256 + r0) * K + sw0;
    const size_t gB1 = (size_t)(bn * 256 + r1) * K + sw1;

    f32x4 acc[4][8];
    #pragma unroll
    for (int mi = 0; mi < 4; ++mi)
        #pragma unroll
        for (int ni = 0; ni < 8; ++ni)
            acc[mi][ni] = (f32x4){0.f, 0.f, 0.f, 0.f};

    auto stage = [&](int b, int kt) {
        const size_t ko = (size_t)kt * 32;
        ushort* L0 = &lds[b * 32768];
        gload_lds16(aH + gA0 + ko, L0 + wave * 1024);
        gload_lds16(aH + gA1 + ko, L0 + wave * 1024 + 512);
        gload_lds16(aL + gA0 + ko, L0 + 8192 + wave * 1024);
        gload_lds16(aL + gA1 + ko, L0 + 8192 + wave * 1024 + 512);
        gload_lds16(wH + gB0 + ko, L0 + 16384 + wave * 1024);
        gload_lds16(wH + gB1 + ko, L0 + 16384 + wave * 1024 + 512);
        gload_lds16(wL + gB0 + ko, L0 + 24576 + wave * 1024);
        gload_lds16(wL + gB1 + ko, L0 + 24576 + wave * 1024 + 512);
    };
    auto compute = [&](int b) {
        const ushort* L0 = &lds[b * 32768];
        bf16x8 ah[4], al[4];
        #pragma unroll
        for (int mi = 0; mi < 4; ++mi) {
            int row = wr * 64 + mi * 16 + l15;
            int o = row * 32 + ((l4 ^ ((row >> 1) & 3)) << 3);
            ah[mi] = *(const bf16x8*)&L0[o];
            al[mi] = *(const bf16x8*)&L0[8192 + o];
        }
        #pragma unroll
        for (int h = 0; h < 2; ++h) {
            bf16x8 bh[4], bl[4];
            #pragma unroll
            for (int q = 0; q < 4; ++q) {
                int row = wc * 128 + (h * 4 + q) * 16 + l15;
                int o = row * 32 + ((l4 ^ ((row >> 1) & 3)) << 3);
                bh[q] = *(const bf16x8*)&L0[16384 + o];
                bl[q] = *(const bf16x8*)&L0[24576 + o];
            }
            __builtin_amdgcn_s_setprio(1);
            #pragma unroll
            for (int mi = 0; mi < 4; ++mi)
                #pragma unroll
                for (int q = 0; q < 4; ++q) {
                    acc[mi][h * 4 + q] = __builtin_amdgcn_mfma_f32_16x16x32_bf16(ah[mi], bh[q], acc[mi][h * 4 + q], 0, 0, 0);
                    acc[mi][h * 4 + q] = __builtin_amdgcn_mfma_f32_16x16x32_bf16(ah[mi], bl[q], acc[mi][h * 4 + q], 0, 0, 0);
                    acc[mi][h * 4 + q] = __builtin_amdgcn_mfma_f32_16x16x32_bf16(al[mi], bh[q], acc[mi][h * 4 + q], 0, 0, 0);
                }
            __builtin_amdgcn_s_setprio(0);
        }
    };

    // prologue
    stage(0, 0);
    asm volatile("s_waitcnt vmcnt(0)");
    __builtin_amdgcn_s_barrier();

    const int nt = K / 32;
    for (int kt = 0; kt < nt - 1; ++kt) {
        stage((kt + 1) & 1, kt + 1);       // issue first: latency under MFMA
        __builtin_amdgcn_sched_barrier(0);
        compute(kt & 1);
        asm volatile("s_waitcnt vmcnt(0)");
        asm volatile("s_waitcnt lgkmcnt(0)\n\ts_barrier" ::: "memory");
    }
    compute((nt - 1) & 1);

    // epilogue (verified r5 C/D mapping)
    #pragma unroll
    for (int ni = 0; ni < 8; ++ni) {
        int col = bn * 256 + wc * 128 + ni * 16 + l15;
        float bv = bias[col];
        #pragma unroll
        for (int mi = 0; mi < 4; ++mi) {
            int rowb = bm * 256 + wr * 64 + mi * 16 + l4 * 4;
            #pragma unroll
            for (int r = 0; r < 4; ++r) {
                float v = acc[mi][ni][r] + bv;
                size_t idx = (size_t)(rowb + r) * N + col;
                if (OUT_SPLIT) {
                    v = fmaxf(v, 0.0f);
                    Chi[idx] = bfhi(v);
                    Clo[idx] = bfhi(v - bfhif(v));
                } else {
                    C32[idx] = v;
                }
            }
        }
    }
}

// ---------------- streaming fp64 repair, stage 1 (8 rows/block, r12) -------
__global__ __launch_bounds__(256) void repair_r1(
    const float* __restrict__ inp,
    const float* __restrict__ W1, const float* __restrict__ b1,
    double* __restrict__ h64,
    const int* __restrict__ risky, const int* __restrict__ cnt, int maxr)
{
    int c = *cnt; if (c > maxr) c = maxr;
    const int by = blockIdx.y;
    if (by * 8 >= c) return;
    __shared__ float Xs[8][4096];
    const int t = threadIdx.x;

    int ridx[8];
    #pragma unroll
    for (int r = 0; r < 8; ++r) {
        int slot = by * 8 + r;
        ridx[r] = risky[slot < c ? slot : (c - 1)];
    }
    #pragma unroll
    for (int i = 0; i < 32; ++i) {
        int lin = t + i * 256;
        int r = lin >> 10, q = lin & 1023;
        *(float4*)&Xs[r][q * 4] = *(const float4*)(inp + (size_t)ridx[r] * 4096 + q * 4);
    }
    __syncthreads();

    const int n0 = blockIdx.x * 256 + t;
    const float* w0 = W1 + (size_t)n0 * 4096;
    double acc[8] = {};

    for (int k = 0; k < 4096; k += 4) {
        float4 a0 = *(const float4*)(w0 + k);
        float xr[8][4];
        #pragma unroll
        for (int r = 0; r < 8; ++r)
            *(float4*)&xr[r][0] = *(const float4*)&Xs[r][k];
        const float* ap0 = &a0.x;
        #pragma unroll
        for (int j = 0; j < 4; ++j) {
            double wd0 = (double)ap0[j];
            #pragma unroll
            for (int r = 0; r < 8; ++r)
                acc[r] = fma(wd0, (double)xr[r][j], acc[r]);
        }
    }

    double bv0 = (double)b1[n0];
    #pragma unroll
    for (int r = 0; r < 8; ++r) {
        int slot = by * 8 + r;
        if (slot < c)
            h64[(size_t)slot * 2048 + n0] = fmax(acc[r] + bv0, 0.0);
    }
}

// ---------------- streaming fp64 repair, stage 2 (r7-verified) -------------
__global__ __launch_bounds__(256) void repair_r2(
    const double* __restrict__ h64,
    const float* __restrict__ W2, const float* __restrict__ b2,
    double* __restrict__ L64,
    const int* __restrict__ cnt, int maxr)
{
    int c = *cnt; if (c > maxr) c = maxr;
    const int by = blockIdx.y;
    if (by * 4 >= c) return;
    __shared__ double Xs[4][2048];
    const int t = threadIdx.x;

    #pragma unroll
    for (int i = 0; i < 16; ++i) {
        int lin = t + i * 256;
        int r = lin >> 10, q = lin & 1023;
        int slot = by * 4 + r; if (slot >= c) slot = c - 1;
        *(double2*)&Xs[r][q * 2] = *(const double2*)(h64 + (size_t)slot * 2048 + q * 2);
    }
    __syncthreads();

    const int n0 = t;
    const int n1 = t + 256;
    const float* w0 = W2 + (size_t)n0 * 2048;
    const float* w1 = W2 + (size_t)n1 * 2048;
    double acc[2][4] = {};

    for (int k = 0; k < 2048; k += 4) {
        float4 a0 = *(const float4*)(w0 + k);
        float4 a1 = *(const float4*)(w1 + k);
        double xr[4][4];
        #pragma unroll
        for (int r = 0; r < 4; ++r) {
            *(double2*)&xr[r][0] = *(const double2*)&Xs[r][k];
            *(double2*)&xr[r][2] = *(const double2*)&Xs[r][k + 2];
        }
        const float* ap0 = &a0.x;
        const float* ap1 = &a1.x;
        #pragma unroll
        for (int j = 0; j < 4; ++j) {
            double wd0 = (double)ap0[j];
            double wd1 = (double)ap1[j];
            #pragma unroll
            for (int r = 0; r < 4; ++r) {
                acc[0][r] = fma(wd0, xr[r][j], acc[0][r]);
                acc[1][r] = fma(wd1, xr[r][j], acc[1][r]);
            }
        }
    }

    double bv0 = (double)b2[n0], bv1 = (double)b2[n1];
    #pragma unroll
    for (int r = 0; r < 4; ++r) {
        int slot = by * 4 + r;
        if (slot < c) {
            L64[(size_t)slot * 512 + n0] = acc[0][r] + bv0;
            L64[(size_t)slot * 512 + n1] = acc[1][r] + bv1;
        }
    }
}

// ---------------- fp64 GEMM (r3-verified; fallback tier only) --------------
template<typename TA, int MODE>
__global__ __launch_bounds__(256, 1) void gemm64(
    const TA* __restrict__ A, int lda,
    const float* __restrict__ W, int ldw,
    const float* __restrict__ bias,
    double* __restrict__ out64, int N, int K)
{
    __shared__ double As[BK][BM + 2];
    __shared__ double Bs[BK][BN + 2];
    const int t  = threadIdx.x;
    const int tm = t >> 4;
    const int tn = t & 15;
    const size_t bm = blockIdx.x;
    const size_t bn = blockIdx.y;
    const TA*    Ab = A + bm * BM * (size_t)lda;
    const float* Wb = W + bn * BN * (size_t)ldw;

    double acc[8][8] = {};

    for (int k0 = 0; k0 < K; k0 += BK) {
        #pragma unroll
        for (int i = 0; i < 2; ++i) {
            int f   = t + i * 256;
            int row = f >> 2;
            int kc  = (f & 3) << 2;
            if constexpr (std::is_same<TA, double>::value) {
                double2 v0 = *(const double2*)(Ab + (size_t)row * lda + k0 + kc);
                double2 v1 = *(const double2*)(Ab + (size_t)row * lda + k0 + kc + 2);
                As[kc + 0][row] = v0.x; As[kc + 1][row] = v0.y;
                As[kc + 2][row] = v1.x; As[kc + 3][row] = v1.y;
            } else {
                float4 va = *(const float4*)(Ab + (size_t)row * lda + k0 + kc);
                As[kc + 0][row] = (double)va.x; As[kc + 1][row] = (double)va.y;
                As[kc + 2][row] = (double)va.z; As[kc + 3][row] = (double)va.w;
            }
            float4 vb = *(const float4*)(Wb + (size_t)row * ldw + k0 + kc);
            Bs[kc + 0][row] = (double)vb.x; Bs[kc + 1][row] = (double)vb.y;
            Bs[kc + 2][row] = (double)vb.z; Bs[kc + 3][row] = (double)vb.w;
        }
        __syncthreads();
        #pragma unroll
        for (int k = 0; k < BK; ++k) {
            double a[8], b[8];
            #pragma unroll
            for (int i = 0; i < 4; ++i) {
                *(double2*)&a[i * 2] = *(const double2*)&As[k][tm * 8 + i * 2];
                *(double2*)&b[i * 2] = *(const double2*)&Bs[k][tn * 8 + i * 2];
            }
            #pragma unroll
            for (int i = 0; i < 8; ++i)
                #pragma unroll
                for (int j = 0; j < 8; ++j)
                    acc[i][j] = fma(a[i], b[j], acc[i][j]);
        }
        __syncthreads();
    }

    double bv[8];
    if (MODE != 2) {
        #pragma unroll
        for (int j = 0; j < 8; ++j) bv[j] = (double)bias[bn * BN + tn * 8 + j];
    }

    #pragma unroll
    for (int i = 0; i < 8; ++i) {
        size_t row  = bm * BM + (size_t)tm * 8 + i;
        size_t base = row * (size_t)N + bn * BN + tn * 8;
        #pragma unroll
        for (int j = 0; j < 8; ++j) {
            double v = acc[i][j];
            if (MODE == 0) out64[base + j] = fmax(v + bv[j], 0.0);
            if (MODE == 1) out64[base + j] = v + bv[j];
            if (MODE == 2) out64[base + j] += v;
        }
    }
}

// ---------------- fp32 top-k + margin flag + gate (in-place safe) ----------
__global__ __launch_bounds__(256) void margin_topk32(
    const float* L, float* O, int ncols,
    const int* __restrict__ kp, int* __restrict__ risky, int* __restrict__ cnt,
    int maxr)
{
    const int wave = threadIdx.x >> 6;
    const int lane = threadIdx.x & 63;
    const int k = *kp;
    const size_t row = (size_t)blockIdx.x * 4 + wave;
    const float* Lr = L + row * (size_t)ncols;

    float v[8];
    *(float4*)&v[0] = *(const float4*)(Lr + lane * 8);
    *(float4*)&v[4] = *(const float4*)(Lr + lane * 8 + 4);
    float w[8];
    #pragma unroll
    for (int j = 0; j < 8; ++j) w[j] = v[j];

    float kth = -3.0e38f, minD = 3.0e38f;
    for (int it = 0; it < k; ++it) {
        float mv = w[0]; int mj = 0;
        #pragma unroll
        for (int j = 1; j < 8; ++j)
            if (w[j] > mv) { mv = w[j]; mj = j; }
        int mi = lane * 8 + mj;
        #pragma unroll
        for (int off = 32; off; off >>= 1) {
            float ov = __shfl_xor(mv, off);
            int   oi = __shfl_xor(mi, off);
            if (ov > mv || (ov == mv && oi < mi)) { mv = ov; mi = oi; }
        }
        kth = mv;
        minD = fminf(minD, fabsf(mv - L02F));
        if ((mi >> 3) == lane) w[mi & 7] = -3.0e38f;
    }
    float nv = w[0];
    #pragma unroll
    for (int j = 1; j < 8; ++j) nv = fmaxf(nv, w[j]);
    #pragma unroll
    for (int off = 32; off; off >>= 1) nv = fmaxf(nv, __shfl_xor(nv, off));

    bool risk = ((kth - nv) < 2.0f * TAU) || (minD < TAU);
    if (risk && lane == 0) {
        int p = atomicAdd(cnt, 1);
        if (p < maxr) risky[p] = (int)row;
    }

    float o[8];
    #pragma unroll
    for (int j = 0; j < 8; ++j)
        o[j] = (v[j] >= kth && v[j] > L02F) ? 1.0f : 0.0f;
    float* Op = O + row * (size_t)ncols + lane * 8;
    *(float4*)&Op[0] = *(const float4*)&o[0];
    *(float4*)&Op[4] = *(const float4*)&o[4];
}

// ---------------- fp64 top-k (r3-verified), direct or gathered -------------
__global__ __launch_bounds__(256) void topk64_kernel(
    const double* __restrict__ L, float* __restrict__ O, int ncols,
    const int* __restrict__ kp,
    const int* __restrict__ risky, const int* __restrict__ cnt, int maxr)
{
    const int wave = threadIdx.x >> 6;
    const int lane = threadIdx.x & 63;
    const int k = *kp;
    size_t pos = (size_t)blockIdx.x * 4 + wave;
    size_t row = pos;
    if (cnt) {
        int c = *cnt; if (c > maxr) c = maxr;
        if ((int)pos >= c) return;
        row = (size_t)risky[pos];
    }
    const double* Lr = L + pos * (size_t)ncols;

    double v[8];
    #pragma unroll
    for (int j = 0; j < 8; ++j) {
        double l = Lr[lane * 8 + j];
        v[j] = 1.0 / (1.0 + exp(-l));
    }
    double w[8];
    #pragma unroll
    for (int j = 0; j < 8; ++j) w[j] = v[j];

    double kth = -1.0e300;
    for (int it = 0; it < k; ++it) {
        double mv = w[0]; int mj = 0;
        #pragma unroll
        for (int j = 1; j < 8; ++j)
            if (w[j] > mv) { mv = w[j]; mj = j; }
        int mi = lane * 8 + mj;
        #pragma unroll
        for (int off = 32; off; off >>= 1) {
            double ov = __shfl_xor(mv, off);
            int    oi = __shfl_xor(mi, off);
            if (ov > mv || (ov == mv && oi < mi)) { mv = ov; mi = oi; }
        }
        kth = mv;
        if ((mi >> 3) == lane) w[mi & 7] = -1.0e300;
    }

    float o[8];
    #pragma unroll
    for (int j = 0; j < 8; ++j)
        o[j] = (v[j] >= kth && v[j] > 0.2) ? 1.0f : 0.0f;
    float* Op = O + row * (size_t)ncols + lane * 8;
    *(float4*)&Op[0] = *(const float4*)&o[0];
    *(float4*)&Op[4] = *(const float4*)&o[4];
}

extern "C" void kernel_launch(void* const* d_in, const int* in_sizes, int n_in,
                              void* d_out, int out_size, void* d_ws, size_t ws_size,
                              hipStream_t stream) {
    const float* inp = (const float*)d_in[0];
    const float* W1  = (const float*)d_in[1];
    const float* b1  = (const float*)d_in[2];
    const float* W2  = (const float*)d_in[3];
    const float* b2  = (const float*)d_in[4];
    const int*   kp  = (const int*)d_in[5];

    const int H = in_sizes[2];              // 2048
    const int F = in_sizes[4];              // 512
    const int D = in_sizes[1] / H;          // 4096
    const int B = in_sizes[0] / D;          // 16384
    float* out = (float*)d_out;

    const int MAXR = 8192;
    const size_t szHpair = (size_t)B * H * 4;        // 128 MiB
    const size_t szW1p   = (size_t)H * D * 4;        // 32 MiB
    const size_t szW2p   = (size_t)F * H * 4;        // 4 MiB
    const size_t szInpP  = (size_t)B * D * 4;        // 256 MiB
    const size_t needMain = szHpair + szW1p + szW2p + (size_t)MAXR * 4 + 256;
    const size_t needA    = needMain + szInpP;
    const bool shapeOK = (D == 4096 && H == 2048 && F == 512 && B == 16384);

    if (shapeOK && ws_size >= needA) {
        ushort* h_hi  = (ushort*)d_ws;
        ushort* h_lo  = h_hi + (size_t)B * H;
        ushort* w1h   = (ushort*)((char*)d_ws + szHpair);
        ushort* w1l   = w1h + (size_t)H * D;
        ushort* w2h   = (ushort*)((char*)d_ws + szHpair + szW1p);
        ushort* w2l   = w2h + (size_t)F * H;
        int*    risky = (int*)((char*)d_ws + szHpair + szW1p + szW2p);
        int*    cnt   = risky + MAXR;
        ushort* inH   = (ushort*)((char*)d_ws + needMain);
        ushort* inL   = inH + (size_t)B * D;
        double* h64   = (double*)d_ws;                        // repair: aliases h pair
        double* L64   = (double*)((char*)d_ws + szHpair);     // repair: aliases W1 pair
        float*  l32   = out;                                  // logits in d_out

        split3_kernel<<<4096, 256, 0, stream>>>(
            inp, inH, inL, (size_t)B * D / 4,
            W1, w1h, w1l, (size_t)H * D / 4,
            W2, w2h, w2l, (size_t)F * H / 4, cnt);
        // GEMM1: 512 blocks (64 bm x 8 bn), K=4096, split-relu out.
        bgemm_256<1><<<512, 512, 0, stream>>>(
            inH, inL, w1h, w1l, b1, h_hi, h_lo, nullptr, H, D, 8);
        // GEMM2: 128 blocks (64 bm x 2 bn), K=2048, fp32 logits out.
        bgemm_256<0><<<128, 512, 0, stream>>>(
            h_hi, h_lo, w2h, w2l, b2, nullptr, nullptr, l32, F, H, 2);
        margin_topk32<<<B / 4, 256, 0, stream>>>(l32, out, F, kp, risky, cnt, MAXR);
        repair_r1<<<dim3(8, MAXR / 8), 256, 0, stream>>>(
            inp, W1, b1, h64, risky, cnt, MAXR);
        repair_r2<<<dim3(1, MAXR / 4), 256, 0, stream>>>(
            h64, W2, b2, L64, cnt, MAXR);
        topk64_kernel<<<MAXR / 4, 256, 0, stream>>>(L64, out, F, kp, risky, cnt, MAXR);
    } else {
        // Fallback: full-fp64 chunked pipeline (verified r3).
        int Hc = H, Bc = 0;
        for (;;) {
            size_t perRow = (size_t)F * 8 + (size_t)Hc * 8;
            Bc = (int)((ws_size / perRow) / BM) * BM;
            if (Bc >= BM || Hc <= BM) break;
            Hc >>= 1;
        }
        if (Bc < BM) Bc = BM;
        if (Bc > B)  Bc = B;
        double* L   = (double*)d_ws;
        double* h64 = L + (size_t)Bc * F;

        for (int b0 = 0; b0 < B; b0 += Bc) {
            int bc = (B - b0 < Bc) ? (B - b0) : Bc;
            for (int h0 = 0; h0 < H; h0 += Hc) {
                int hc = (H - h0 < Hc) ? (H - h0) : Hc;
                gemm64<float, 0><<<dim3(bc / BM, hc / BN), 256, 0, stream>>>(
                    inp + (size_t)b0 * D, D, W1 + (size_t)h0 * D, D, b1 + h0,
                    h64, hc, D);
                if (h0 == 0)
                    gemm64<double, 1><<<dim3(bc / BM, F / BN), 256, 0, stream>>>(
                        h64, hc, W2 + h0, H, b2, L, F, hc);
                else
                    gemm64<double, 2><<<dim3(bc / BM, F / BN), 256, 0, stream>>>(
                        h64, hc, W2 + h0, H, b2, L, F, hc);
            }
            topk64_kernel<<<bc / 4, 256, 0, stream>>>(
                L, out + (size_t)b0 * F, F, kp, nullptr, nullptr, 0);
        }
    }
}

// Round 17
// 1232.198 us; speedup vs baseline: 1.0361x; 1.0361x over previous
//
#include <hip/hip_runtime.h>
#include <math.h>
#include <type_traits>

// Fused MLP head with BINARY output (per-row top-k gate + 0.2 hardlim).
// Verified architecture: bf16-split(3-product) MFMA fast pass -> logit-margin
// flags (TAU=1e-4) -> streaming fp64 repair of flagged rows -> exact gate.
// r16: REVERT to r14 config (best verified: 1233us). r15's GEMM2 unification
//      regressed: 256x256 tiles on 16384x512 output = 128 wgs = half the CUs
//      idle. GEMM2 back to r11's 256x128/3-buf bgemm_glds (256 wgs).
//      GEMM1 (58.6% MfmaUtil) is at 94% of the m201-class structural ceiling;
//      split3 at HBM floor; repairs latency-bound. This is the bank-it round.

#define BM 128
#define BN 128
#define BK 16      // fp64 fallback K-step

#define TAU   1.0e-4f
#define L02F -1.3862943611198906f   /* ln(0.2/0.8) */

typedef __attribute__((ext_vector_type(8))) short  bf16x8;
typedef __attribute__((ext_vector_type(8))) ushort u16x8;
typedef __attribute__((ext_vector_type(4))) float  f32x4;

__device__ inline ushort bfhi(float f)   { return (ushort)(__float_as_uint(f) >> 16); }
__device__ inline float  bfhif(float f)  { return __uint_as_float(__float_as_uint(f) & 0xFFFF0000u); }

__device__ inline void gload_lds16(const void* g, void* l) {
    __builtin_amdgcn_global_load_lds(
        (const __attribute__((address_space(1))) unsigned int*)g,
        (__attribute__((address_space(3))) unsigned int*)l, 16, 0, 0);
}

// ---------------- fused fp32 -> (hi,lo) bf16 split over 3 arrays -----------
__global__ __launch_bounds__(256) void split3_kernel(
    const float* __restrict__ s0, ushort* __restrict__ h0, ushort* __restrict__ l0, size_t n0,
    const float* __restrict__ s1, ushort* __restrict__ h1, ushort* __restrict__ l1, size_t n1,
    const float* __restrict__ s2, ushort* __restrict__ h2, ushort* __restrict__ l2, size_t n2,
    int* cnt)
{
    if (blockIdx.x == 0 && threadIdx.x == 0) *cnt = 0;
    size_t i = (size_t)blockIdx.x * 256 + threadIdx.x;
    const size_t stride = (size_t)gridDim.x * 256;
    const size_t total = n0 + n1 + n2;
    for (; i < total; i += stride) {
        const float* s; ushort* h; ushort* l; size_t j;
        if (i < n0)            { s = s0; h = h0; l = l0; j = i; }
        else if (i < n0 + n1)  { s = s1; h = h1; l = l1; j = i - n0; }
        else                   { s = s2; h = h2; l = l2; j = i - n0 - n1; }
        float4 v = ((const float4*)s)[j];
        ushort4 hh, ll;
        hh.x = bfhi(v.x); ll.x = bfhi(v.x - bfhif(v.x));
        hh.y = bfhi(v.y); ll.y = bfhi(v.y - bfhif(v.y));
        hh.z = bfhi(v.z); ll.z = bfhi(v.z - bfhif(v.z));
        hh.w = bfhi(v.w); ll.w = bfhi(v.w - bfhif(v.w));
        ((ushort4*)h)[j] = hh;
        ((ushort4*)l)[j] = ll;
    }
}

// ---------------- GEMM1: 256x256 tile, 2x64KB bufs, gload-staged (r12) -----
// C(split) = relu(inp @ W1^T + b1). Fixed 16384x2048x4096, BK=32.
// 512 thr (8 waves, 4m x 2n; wave tile 64x128).
__global__ __launch_bounds__(512, 2) void bgemm1_256(
    const ushort* __restrict__ aH, const ushort* __restrict__ aL,
    const ushort* __restrict__ wH, const ushort* __restrict__ wL,
    const float* __restrict__ b1,
    ushort* __restrict__ Chi, ushort* __restrict__ Clo)
{
    __shared__ ushort lds[65536];          // 2 bufs x 32768 ush (64 KB each)
    const int t    = threadIdx.x;
    const int lane = t & 63;
    const int wave = t >> 6;
    const int wr   = wave >> 1;            // 0..3 (64-row block)
    const int wc   = wave & 1;             // 0..1 (128-col block)
    const int l15  = lane & 15;
    const int l4   = lane >> 4;

    // XCD: contiguous bm per XCD, bn fastest. 512 blocks (64 bm x 8 bn).
    const int bid = blockIdx.x;
    const int xcd = bid & 7;
    const int j   = bid >> 3;              // 0..63
    const int bm  = xcd * 8 + (j >> 3);    // 0..63
    const int bn  = j & 7;                 // 0..7

    // staging: per wave 8 gloads, rows wave*32..+31 of each region
    const int cq = lane & 3;
    const int r0 = wave * 32 + (lane >> 2);
    const int r1 = r0 + 16;
    const size_t sw0 = (size_t)((cq ^ ((r0 >> 1) & 3)) * 8);
    const size_t sw1 = (size_t)((cq ^ ((r1 >> 1) & 3)) * 8);
    const size_t gA0 = (size_t)(bm * 256 + r0) * 4096 + sw0;
    const size_t gA1 = (size_t)(bm * 256 + r1) * 4096 + sw1;
    const size_t gB0 = (size_t)(bn * 256 + r0) * 4096 + sw0;
    const size_t gB1 = (size_t)(bn * 256 + r1) * 4096 + sw1;

    f32x4 acc[4][8];
    #pragma unroll
    for (int mi = 0; mi < 4; ++mi)
        #pragma unroll
        for (int ni = 0; ni < 8; ++ni)
            acc[mi][ni] = (f32x4){0.f, 0.f, 0.f, 0.f};

    auto stage = [&](int b, int kt) {
        const size_t ko = (size_t)kt * 32;
        ushort* L0 = &lds[b * 32768];
        gload_lds16(aH + gA0 + ko, L0 + wave * 1024);
        gload_lds16(aH + gA1 + ko, L0 + wave * 1024 + 512);
        gload_lds16(aL + gA0 + ko, L0 + 8192 + wave * 1024);
        gload_lds16(aL + gA1 + ko, L0 + 8192 + wave * 1024 + 512);
        gload_lds16(wH + gB0 + ko, L0 + 16384 + wave * 1024);
        gload_lds16(wH + gB1 + ko, L0 + 16384 + wave * 1024 + 512);
        gload_lds16(wL + gB0 + ko, L0 + 24576 + wave * 1024);
        gload_lds16(wL + gB1 + ko, L0 + 24576 + wave * 1024 + 512);
    };
    auto compute = [&](int b) {
        const ushort* L0 = &lds[b * 32768];
        bf16x8 ah[4], al[4];
        #pragma unroll
        for (int mi = 0; mi < 4; ++mi) {
            int row = wr * 64 + mi * 16 + l15;
            int o = row * 32 + ((l4 ^ ((row >> 1) & 3)) << 3);
            ah[mi] = *(const bf16x8*)&L0[o];
            al[mi] = *(const bf16x8*)&L0[8192 + o];
        }
        #pragma unroll
        for (int h = 0; h < 2; ++h) {
            bf16x8 bh[4], bl[4];
            #pragma unroll
            for (int q = 0; q < 4; ++q) {
                int row = wc * 128 + (h * 4 + q) * 16 + l15;
                int o = row * 32 + ((l4 ^ ((row >> 1) & 3)) << 3);
                bh[q] = *(const bf16x8*)&L0[16384 + o];
                bl[q] = *(const bf16x8*)&L0[24576 + o];
            }
            __builtin_amdgcn_s_setprio(1);
            #pragma unroll
            for (int mi = 0; mi < 4; ++mi)
                #pragma unroll
                for (int q = 0; q < 4; ++q) {
                    acc[mi][h * 4 + q] = __builtin_amdgcn_mfma_f32_16x16x32_bf16(ah[mi], bh[q], acc[mi][h * 4 + q], 0, 0, 0);
                    acc[mi][h * 4 + q] = __builtin_amdgcn_mfma_f32_16x16x32_bf16(ah[mi], bl[q], acc[mi][h * 4 + q], 0, 0, 0);
                    acc[mi][h * 4 + q] = __builtin_amdgcn_mfma_f32_16x16x32_bf16(al[mi], bh[q], acc[mi][h * 4 + q], 0, 0, 0);
                }
            __builtin_amdgcn_s_setprio(0);
        }
    };

    // prologue
    stage(0, 0);
    asm volatile("s_waitcnt vmcnt(0)");
    __builtin_amdgcn_s_barrier();

    const int nt = 128;  // 4096/32
    for (int kt = 0; kt < nt - 1; ++kt) {
        stage((kt + 1) & 1, kt + 1);       // issue first: latency under MFMA
        __builtin_amdgcn_sched_barrier(0);
        compute(kt & 1);
        asm volatile("s_waitcnt vmcnt(0)");
        asm volatile("s_waitcnt lgkmcnt(0)\n\ts_barrier" ::: "memory");
    }
    compute((nt - 1) & 1);

    // epilogue: relu + split-store (verified r5 C/D mapping)
    #pragma unroll
    for (int ni = 0; ni < 8; ++ni) {
        int col = bn * 256 + wc * 128 + ni * 16 + l15;
        float bv = b1[col];
        #pragma unroll
        for (int mi = 0; mi < 4; ++mi) {
            int rowb = bm * 256 + wr * 64 + mi * 16 + l4 * 4;
            #pragma unroll
            for (int r = 0; r < 4; ++r) {
                float v = fmaxf(acc[mi][ni][r] + bv, 0.0f);
                size_t idx = (size_t)(rowb + r) * 2048 + col;
                Chi[idx] = bfhi(v);
                Clo[idx] = bfhi(v - bfhif(v));
            }
        }
    }
}

// ---------------- bgemm_glds (r11-verified): GEMM2 path --------------------
template<int OUT_SPLIT>
__global__ __launch_bounds__(512, 2) void bgemm_glds(
    const ushort* __restrict__ aH, const ushort* __restrict__ aL,
    const ushort* __restrict__ wH, const ushort* __restrict__ wL,
    const float* __restrict__ bias,
    ushort* __restrict__ Chi, ushort* __restrict__ Clo,
    float* __restrict__ C32,
    int N, int K, int nbm, int nbn)
{
    __shared__ ushort lds[73728];
    const int t    = threadIdx.x;
    const int lane = t & 63;
    const int wave = t >> 6;
    const int wr   = wave >> 1;
    const int wc   = wave & 1;
    const int l15  = lane & 15;
    const int l4   = lane >> 4;

    const int bid = blockIdx.x;
    const int xcd = bid & 7;
    const int j   = bid >> 3;
    const int bm  = xcd * (nbm >> 3) + j / nbn;
    const int bn  = j % nbn;

    const int c   = lane & 3;
    const int rA0 = (wave * 2 + 0) * 16 + (lane >> 2);
    const int rA1 = (wave * 2 + 1) * 16 + (lane >> 2);
    const int rB  = wave * 16 + (lane >> 2);
    const size_t offA0 = (size_t)(bm * 256 + rA0) * K + (size_t)((c ^ ((rA0 >> 1) & 3)) * 8);
    const size_t offA1 = (size_t)(bm * 256 + rA1) * K + (size_t)((c ^ ((rA1 >> 1) & 3)) * 8);
    const size_t offB  = (size_t)(bn * 128 + rB ) * K + (size_t)((c ^ ((rB  >> 1) & 3)) * 8);
    const ushort* sAh0 = aH + offA0; const ushort* sAl0 = aL + offA0;
    const ushort* sAh1 = aH + offA1; const ushort* sAl1 = aL + offA1;
    const ushort* sBh  = wH + offB;  const ushort* sBl  = wL + offB;

    f32x4 acc[4][4];
    #pragma unroll
    for (int mi = 0; mi < 4; ++mi)
        #pragma unroll
        for (int ni = 0; ni < 4; ++ni)
            acc[mi][ni] = (f32x4){0.f, 0.f, 0.f, 0.f};

    auto stage = [&](int b, int kt) {
        const size_t ko = (size_t)kt * 32;
        ushort* L0 = &lds[b * 24576];
        gload_lds16(sAh0 + ko, L0 + (wave * 2 + 0) * 512);
        gload_lds16(sAh1 + ko, L0 + (wave * 2 + 1) * 512);
        gload_lds16(sAl0 + ko, L0 + 8192 + (wave * 2 + 0) * 512);
        gload_lds16(sAl1 + ko, L0 + 8192 + (wave * 2 + 1) * 512);
        gload_lds16(sBh + ko,  L0 + 16384 + wave * 512);
        gload_lds16(sBl + ko,  L0 + 20480 + wave * 512);
    };
    auto frag_read = [&](int b, bf16x8 ah[4], bf16x8 al[4], bf16x8 bh[4], bf16x8 bl[4]) {
        const ushort* L0 = &lds[b * 24576];
        #pragma unroll
        for (int mi = 0; mi < 4; ++mi) {
            int row = wr * 64 + mi * 16 + l15;
            int o = row * 32 + ((l4 ^ ((row >> 1) & 3)) << 3);
            ah[mi] = *(const bf16x8*)&L0[o];
            al[mi] = *(const bf16x8*)&L0[8192 + o];
        }
        #pragma unroll
        for (int ni = 0; ni < 4; ++ni) {
            int row = wc * 64 + ni * 16 + l15;
            int o = row * 32 + ((l4 ^ ((row >> 1) & 3)) << 3);
            bh[ni] = *(const bf16x8*)&L0[16384 + o];
            bl[ni] = *(const bf16x8*)&L0[20480 + o];
        }
    };
    auto do_mfma = [&](bf16x8 ah[4], bf16x8 al[4], bf16x8 bh[4], bf16x8 bl[4]) {
        __builtin_amdgcn_s_setprio(1);
        #pragma unroll
        for (int mi = 0; mi < 4; ++mi)
            #pragma unroll
            for (int ni = 0; ni < 4; ++ni) {
                acc[mi][ni] = __builtin_amdgcn_mfma_f32_16x16x32_bf16(ah[mi], bh[ni], acc[mi][ni], 0, 0, 0);
                acc[mi][ni] = __builtin_amdgcn_mfma_f32_16x16x32_bf16(ah[mi], bl[ni], acc[mi][ni], 0, 0, 0);
                acc[mi][ni] = __builtin_amdgcn_mfma_f32_16x16x32_bf16(al[mi], bh[ni], acc[mi][ni], 0, 0, 0);
            }
        __builtin_amdgcn_s_setprio(0);
    };

    stage(0, 0);
    stage(1, 1);
    asm volatile("s_waitcnt vmcnt(6)");
    __builtin_amdgcn_s_barrier();

    const int nt = K / 32;
    bf16x8 ah[4], al[4], bh[4], bl[4];

    for (int kt = 0; kt < nt - 2; ++kt) {
        frag_read(kt % 3, ah, al, bh, bl);
        stage((kt + 2) % 3, kt + 2);
        __builtin_amdgcn_sched_barrier(0);
        do_mfma(ah, al, bh, bl);
        asm volatile("s_waitcnt vmcnt(6)");
        asm volatile("s_waitcnt lgkmcnt(0)\n\ts_barrier" ::: "memory");
    }
    {
        frag_read((nt - 2) % 3, ah, al, bh, bl);
        do_mfma(ah, al, bh, bl);
        asm volatile("s_waitcnt vmcnt(0)");
        asm volatile("s_waitcnt lgkmcnt(0)\n\ts_barrier" ::: "memory");
    }
    {
        frag_read((nt - 1) % 3, ah, al, bh, bl);
        do_mfma(ah, al, bh, bl);
    }

    #pragma unroll
    for (int ni = 0; ni < 4; ++ni) {
        int col = bn * 128 + wc * 64 + ni * 16 + l15;
        float bv = bias[col];
        #pragma unroll
        for (int mi = 0; mi < 4; ++mi) {
            int rowb = bm * 256 + wr * 64 + mi * 16 + l4 * 4;
            #pragma unroll
            for (int r = 0; r < 4; ++r) {
                float v = acc[mi][ni][r] + bv;
                size_t idx = (size_t)(rowb + r) * N + col;
                if (OUT_SPLIT) {
                    v = fmaxf(v, 0.0f);
                    Chi[idx] = bfhi(v);
                    Clo[idx] = bfhi(v - bfhif(v));
                } else {
                    C32[idx] = v;
                }
            }
        }
    }
}

// ---------------- streaming fp64 repair, stage 1 (8 rows/block, r12) -------
__global__ __launch_bounds__(256) void repair_r1(
    const float* __restrict__ inp,
    const float* __restrict__ W1, const float* __restrict__ b1,
    double* __restrict__ h64,
    const int* __restrict__ risky, const int* __restrict__ cnt, int maxr)
{
    int c = *cnt; if (c > maxr) c = maxr;
    const int by = blockIdx.y;
    if (by * 8 >= c) return;
    __shared__ float Xs[8][4096];
    const int t = threadIdx.x;

    int ridx[8];
    #pragma unroll
    for (int r = 0; r < 8; ++r) {
        int slot = by * 8 + r;
        ridx[r] = risky[slot < c ? slot : (c - 1)];
    }
    #pragma unroll
    for (int i = 0; i < 32; ++i) {
        int lin = t + i * 256;
        int r = lin >> 10, q = lin & 1023;
        *(float4*)&Xs[r][q * 4] = *(const float4*)(inp + (size_t)ridx[r] * 4096 + q * 4);
    }
    __syncthreads();

    const int n0 = blockIdx.x * 256 + t;
    const float* w0 = W1 + (size_t)n0 * 4096;
    double acc[8] = {};

    for (int k = 0; k < 4096; k += 4) {
        float4 a0 = *(const float4*)(w0 + k);
        float xr[8][4];
        #pragma unroll
        for (int r = 0; r < 8; ++r)
            *(float4*)&xr[r][0] = *(const float4*)&Xs[r][k];
        const float* ap0 = &a0.x;
        #pragma unroll
        for (int j = 0; j < 4; ++j) {
            double wd0 = (double)ap0[j];
            #pragma unroll
            for (int r = 0; r < 8; ++r)
                acc[r] = fma(wd0, (double)xr[r][j], acc[r]);
        }
    }

    double bv0 = (double)b1[n0];
    #pragma unroll
    for (int r = 0; r < 8; ++r) {
        int slot = by * 8 + r;
        if (slot < c)
            h64[(size_t)slot * 2048 + n0] = fmax(acc[r] + bv0, 0.0);
    }
}

// ---------------- streaming fp64 repair, stage 2 (r7-verified) -------------
__global__ __launch_bounds__(256) void repair_r2(
    const double* __restrict__ h64,
    const float* __restrict__ W2, const float* __restrict__ b2,
    double* __restrict__ L64,
    const int* __restrict__ cnt, int maxr)
{
    int c = *cnt; if (c > maxr) c = maxr;
    const int by = blockIdx.y;
    if (by * 4 >= c) return;
    __shared__ double Xs[4][2048];
    const int t = threadIdx.x;

    #pragma unroll
    for (int i = 0; i < 16; ++i) {
        int lin = t + i * 256;
        int r = lin >> 10, q = lin & 1023;
        int slot = by * 4 + r; if (slot >= c) slot = c - 1;
        *(double2*)&Xs[r][q * 2] = *(const double2*)(h64 + (size_t)slot * 2048 + q * 2);
    }
    __syncthreads();

    const int n0 = t;
    const int n1 = t + 256;
    const float* w0 = W2 + (size_t)n0 * 2048;
    const float* w1 = W2 + (size_t)n1 * 2048;
    double acc[2][4] = {};

    for (int k = 0; k < 2048; k += 4) {
        float4 a0 = *(const float4*)(w0 + k);
        float4 a1 = *(const float4*)(w1 + k);
        double xr[4][4];
        #pragma unroll
        for (int r = 0; r < 4; ++r) {
            *(double2*)&xr[r][0] = *(const double2*)&Xs[r][k];
            *(double2*)&xr[r][2] = *(const double2*)&Xs[r][k + 2];
        }
        const float* ap0 = &a0.x;
        const float* ap1 = &a1.x;
        #pragma unroll
        for (int j = 0; j < 4; ++j) {
            double wd0 = (double)ap0[j];
            double wd1 = (double)ap1[j];
            #pragma unroll
            for (int r = 0; r < 4; ++r) {
                acc[0][r] = fma(wd0, xr[r][j], acc[0][r]);
                acc[1][r] = fma(wd1, xr[r][j], acc[1][r]);
            }
        }
    }

    double bv0 = (double)b2[n0], bv1 = (double)b2[n1];
    #pragma unroll
    for (int r = 0; r < 4; ++r) {
        int slot = by * 4 + r;
        if (slot < c) {
            L64[(size_t)slot * 512 + n0] = acc[0][r] + bv0;
            L64[(size_t)slot * 512 + n1] = acc[1][r] + bv1;
        }
    }
}

// ---------------- fp64 GEMM (r3-verified; fallback tier only) --------------
template<typename TA, int MODE>
__global__ __launch_bounds__(256, 1) void gemm64(
    const TA* __restrict__ A, int lda,
    const float* __restrict__ W, int ldw,
    const float* __restrict__ bias,
    double* __restrict__ out64, int N, int K)
{
    __shared__ double As[BK][BM + 2];
    __shared__ double Bs[BK][BN + 2];
    const int t  = threadIdx.x;
    const int tm = t >> 4;
    const int tn = t & 15;
    const size_t bm = blockIdx.x;
    const size_t bn = blockIdx.y;
    const TA*    Ab = A + bm * BM * (size_t)lda;
    const float* Wb = W + bn * BN * (size_t)ldw;

    double acc[8][8] = {};

    for (int k0 = 0; k0 < K; k0 += BK) {
        #pragma unroll
        for (int i = 0; i < 2; ++i) {
            int f   = t + i * 256;
            int row = f >> 2;
            int kc  = (f & 3) << 2;
            if constexpr (std::is_same<TA, double>::value) {
                double2 v0 = *(const double2*)(Ab + (size_t)row * lda + k0 + kc);
                double2 v1 = *(const double2*)(Ab + (size_t)row * lda + k0 + kc + 2);
                As[kc + 0][row] = v0.x; As[kc + 1][row] = v0.y;
                As[kc + 2][row] = v1.x; As[kc + 3][row] = v1.y;
            } else {
                float4 va = *(const float4*)(Ab + (size_t)row * lda + k0 + kc);
                As[kc + 0][row] = (double)va.x; As[kc + 1][row] = (double)va.y;
                As[kc + 2][row] = (double)va.z; As[kc + 3][row] = (double)va.w;
            }
            float4 vb = *(const float4*)(Wb + (size_t)row * ldw + k0 + kc);
            Bs[kc + 0][row] = (double)vb.x; Bs[kc + 1][row] = (double)vb.y;
            Bs[kc + 2][row] = (double)vb.z; Bs[kc + 3][row] = (double)vb.w;
        }
        __syncthreads();
        #pragma unroll
        for (int k = 0; k < BK; ++k) {
            double a[8], b[8];
            #pragma unroll
            for (int i = 0; i < 4; ++i) {
                *(double2*)&a[i * 2] = *(const double2*)&As[k][tm * 8 + i * 2];
                *(double2*)&b[i * 2] = *(const double2*)&Bs[k][tn * 8 + i * 2];
            }
            #pragma unroll
            for (int i = 0; i < 8; ++i)
                #pragma unroll
                for (int j = 0; j < 8; ++j)
                    acc[i][j] = fma(a[i], b[j], acc[i][j]);
        }
        __syncthreads();
    }

    double bv[8];
    if (MODE != 2) {
        #pragma unroll
        for (int j = 0; j < 8; ++j) bv[j] = (double)bias[bn * BN + tn * 8 + j];
    }

    #pragma unroll
    for (int i = 0; i < 8; ++i) {
        size_t row  = bm * BM + (size_t)tm * 8 + i;
        size_t base = row * (size_t)N + bn * BN + tn * 8;
        #pragma unroll
        for (int j = 0; j < 8; ++j) {
            double v = acc[i][j];
            if (MODE == 0) out64[base + j] = fmax(v + bv[j], 0.0);
            if (MODE == 1) out64[base + j] = v + bv[j];
            if (MODE == 2) out64[base + j] += v;
        }
    }
}

// ---------------- fp32 top-k + margin flag + gate (in-place safe) ----------
__global__ __launch_bounds__(256) void margin_topk32(
    const float* L, float* O, int ncols,
    const int* __restrict__ kp, int* __restrict__ risky, int* __restrict__ cnt,
    int maxr)
{
    const int wave = threadIdx.x >> 6;
    const int lane = threadIdx.x & 63;
    const int k = *kp;
    const size_t row = (size_t)blockIdx.x * 4 + wave;
    const float* Lr = L + row * (size_t)ncols;

    float v[8];
    *(float4*)&v[0] = *(const float4*)(Lr + lane * 8);
    *(float4*)&v[4] = *(const float4*)(Lr + lane * 8 + 4);
    float w[8];
    #pragma unroll
    for (int j = 0; j < 8; ++j) w[j] = v[j];

    float kth = -3.0e38f, minD = 3.0e38f;
    for (int it = 0; it < k; ++it) {
        float mv = w[0]; int mj = 0;
        #pragma unroll
        for (int j = 1; j < 8; ++j)
            if (w[j] > mv) { mv = w[j]; mj = j; }
        int mi = lane * 8 + mj;
        #pragma unroll
        for (int off = 32; off; off >>= 1) {
            float ov = __shfl_xor(mv, off);
            int   oi = __shfl_xor(mi, off);
            if (ov > mv || (ov == mv && oi < mi)) { mv = ov; mi = oi; }
        }
        kth = mv;
        minD = fminf(minD, fabsf(mv - L02F));
        if ((mi >> 3) == lane) w[mi & 7] = -3.0e38f;
    }
    float nv = w[0];
    #pragma unroll
    for (int j = 1; j < 8; ++j) nv = fmaxf(nv, w[j]);
    #pragma unroll
    for (int off = 32; off; off >>= 1) nv = fmaxf(nv, __shfl_xor(nv, off));

    bool risk = ((kth - nv) < 2.0f * TAU) || (minD < TAU);
    if (risk && lane == 0) {
        int p = atomicAdd(cnt, 1);
        if (p < maxr) risky[p] = (int)row;
    }

    float o[8];
    #pragma unroll
    for (int j = 0; j < 8; ++j)
        o[j] = (v[j] >= kth && v[j] > L02F) ? 1.0f : 0.0f;
    float* Op = O + row * (size_t)ncols + lane * 8;
    *(float4*)&Op[0] = *(const float4*)&o[0];
    *(float4*)&Op[4] = *(const float4*)&o[4];
}

// ---------------- fp64 top-k (r3-verified), direct or gathered -------------
__global__ __launch_bounds__(256) void topk64_kernel(
    const double* __restrict__ L, float* __restrict__ O, int ncols,
    const int* __restrict__ kp,
    const int* __restrict__ risky, const int* __restrict__ cnt, int maxr)
{
    const int wave = threadIdx.x >> 6;
    const int lane = threadIdx.x & 63;
    const int k = *kp;
    size_t pos = (size_t)blockIdx.x * 4 + wave;
    size_t row = pos;
    if (cnt) {
        int c = *cnt; if (c > maxr) c = maxr;
        if ((int)pos >= c) return;
        row = (size_t)risky[pos];
    }
    const double* Lr = L + pos * (size_t)ncols;

    double v[8];
    #pragma unroll
    for (int j = 0; j < 8; ++j) {
        double l = Lr[lane * 8 + j];
        v[j] = 1.0 / (1.0 + exp(-l));
    }
    double w[8];
    #pragma unroll
    for (int j = 0; j < 8; ++j) w[j] = v[j];

    double kth = -1.0e300;
    for (int it = 0; it < k; ++it) {
        double mv = w[0]; int mj = 0;
        #pragma unroll
        for (int j = 1; j < 8; ++j)
            if (w[j] > mv) { mv = w[j]; mj = j; }
        int mi = lane * 8 + mj;
        #pragma unroll
        for (int off = 32; off; off >>= 1) {
            double ov = __shfl_xor(mv, off);
            int    oi = __shfl_xor(mi, off);
            if (ov > mv || (ov == mv && oi < mi)) { mv = ov; mi = oi; }
        }
        kth = mv;
        if ((mi >> 3) == lane) w[mi & 7] = -1.0e300;
    }

    float o[8];
    #pragma unroll
    for (int j = 0; j < 8; ++j)
        o[j] = (v[j] >= kth && v[j] > 0.2) ? 1.0f : 0.0f;
    float* Op = O + row * (size_t)ncols + lane * 8;
    *(float4*)&Op[0] = *(const float4*)&o[0];
    *(float4*)&Op[4] = *(const float4*)&o[4];
}

extern "C" void kernel_launch(void* const* d_in, const int* in_sizes, int n_in,
                              void* d_out, int out_size, void* d_ws, size_t ws_size,
                              hipStream_t stream) {
    const float* inp = (const float*)d_in[0];
    const float* W1  = (const float*)d_in[1];
    const float* b1  = (const float*)d_in[2];
    const float* W2  = (const float*)d_in[3];
    const float* b2  = (const float*)d_in[4];
    const int*   kp  = (const int*)d_in[5];

    const int H = in_sizes[2];              // 2048
    const int F = in_sizes[4];              // 512
    const int D = in_sizes[1] / H;          // 4096
    const int B = in_sizes[0] / D;          // 16384
    float* out = (float*)d_out;

    const int MAXR = 8192;
    const size_t szHpair = (size_t)B * H * 4;        // 128 MiB
    const size_t szW1p   = (size_t)H * D * 4;        // 32 MiB
    const size_t szW2p   = (size_t)F * H * 4;        // 4 MiB
    const size_t szInpP  = (size_t)B * D * 4;        // 256 MiB
    const size_t needMain = szHpair + szW1p + szW2p + (size_t)MAXR * 4 + 256;
    const size_t needA    = needMain + szInpP;
    const bool shapeOK = (D == 4096 && H == 2048 && F == 512 && B == 16384);

    if (shapeOK && ws_size >= needA) {
        ushort* h_hi  = (ushort*)d_ws;
        ushort* h_lo  = h_hi + (size_t)B * H;
        ushort* w1h   = (ushort*)((char*)d_ws + szHpair);
        ushort* w1l   = w1h + (size_t)H * D;
        ushort* w2h   = (ushort*)((char*)d_ws + szHpair + szW1p);
        ushort* w2l   = w2h + (size_t)F * H;
        int*    risky = (int*)((char*)d_ws + szHpair + szW1p + szW2p);
        int*    cnt   = risky + MAXR;
        ushort* inH   = (ushort*)((char*)d_ws + needMain);
        ushort* inL   = inH + (size_t)B * D;
        double* h64   = (double*)d_ws;                        // repair: aliases h pair
        double* L64   = (double*)((char*)d_ws + szHpair);     // repair: aliases W1 pair
        float*  l32   = out;                                  // logits in d_out

        split3_kernel<<<4096, 256, 0, stream>>>(
            inp, inH, inL, (size_t)B * D / 4,
            W1, w1h, w1l, (size_t)H * D / 4,
            W2, w2h, w2l, (size_t)F * H / 4, cnt);
        bgemm1_256<<<512, 512, 0, stream>>>(inH, inL, w1h, w1l, b1, h_hi, h_lo);
        bgemm_glds<0><<<256, 512, 0, stream>>>(
            h_hi, h_lo, w2h, w2l, b2, nullptr, nullptr, l32, F, H, B / 256, F / 128);
        margin_topk32<<<B / 4, 256, 0, stream>>>(l32, out, F, kp, risky, cnt, MAXR);
        repair_r1<<<dim3(8, MAXR / 8), 256, 0, stream>>>(
            inp, W1, b1, h64, risky, cnt, MAXR);
        repair_r2<<<dim3(1, MAXR / 4), 256, 0, stream>>>(
            h64, W2, b2, L64, cnt, MAXR);
        topk64_kernel<<<MAXR / 4, 256, 0, stream>>>(L64, out, F, kp, risky, cnt, MAXR);
    } else {
        // Fallback: full-fp64 chunked pipeline (verified r3).
        int Hc = H, Bc = 0;
        for (;;) {
            size_t perRow = (size_t)F * 8 + (size_t)Hc * 8;
            Bc = (int)((ws_size / perRow) / BM) * BM;
            if (Bc >= BM || Hc <= BM) break;
            Hc >>= 1;
        }
        if (Bc < BM) Bc = BM;
        if (Bc > B)  Bc = B;
        double* L   = (double*)d_ws;
        double* h64 = L + (size_t)Bc * F;

        for (int b0 = 0; b0 < B; b0 += Bc) {
            int bc = (B - b0 < Bc) ? (B - b0) : Bc;
            for (int h0 = 0; h0 < H; h0 += Hc) {
                int hc = (H - h0 < Hc) ? (H - h0) : Hc;
                gemm64<float, 0><<<dim3(bc / BM, hc / BN), 256, 0, stream>>>(
                    inp + (size_t)b0 * D, D, W1 + (size_t)h0 * D, D, b1 + h0,
                    h64, hc, D);
                if (h0 == 0)
                    gemm64<double, 1><<<dim3(bc / BM, F / BN), 256, 0, stream>>>(
                        h64, hc, W2 + h0, H, b2, L, F, hc);
                else
                    gemm64<double, 2><<<dim3(bc / BM, F / BN), 256, 0, stream>>>(
                        h64, hc, W2 + h0, H, b2, L, F, hc);
            }
            topk64_kernel<<<bc / 4, 256, 0, stream>>>(
                L, out + (size_t)b0 * F, F, kp, nullptr, nullptr, 0);
        }
    }
}